// Round 1
// baseline (707.986 us; speedup 1.0000x reference)
//
#include <hip/hip_runtime.h>
#include <hip/hip_bf16.h>
#include <stdint.h>

// Problem constants (B=8, T=4096, D=1024, H=1024)
#define B_   8
#define T_   4096
#define D_   1024
#define H_   1024
#define M_   (B_ * T_)   // 32768 rows
#define NC_  64          // scan chunks
#define TC_  64          // steps per chunk

// SEMANTICS LOCKED (r13 PASS, absmax 0.5): np-ref accumulation = KC512
// two-panel FMA. fixup_kc512 + 1e-3 flag guard must not change.
// r14: truncation split + v_perm packing for A (kept verbatim).
// r15 (this round): gemm_cv restructured —
//   (a) T2 XOR-swizzle: A and B LDS tiles become [row][128B] combined hi|lo
//       with 16B-chunk position c = s ^ (row&7). Fragment ds_read_b128 was
//       8-way bank-conflicted (64B row stride, SQ_LDS_BANK_CONFLICT=3.35e7
//       ~10% of cycles); now 2-way (free). B arrives via global_load_lds
//       (linear dest), so prep_w pre-swizzles the GLOBAL image (rule #21:
//       both-sides-or-neither) into packed 8KB per-(mat,nt,kt) blocks.
//   (b) T3-minimum double-buffer: issue x-loads + B-gloads for step t+1
//       BEFORE ds_read+MFMA of step t; split/ds_write A(t+1) after MFMA
//       (T14 issue-early/write-late); ONE barrier per K-step. The old shape
//       issued gloads immediately before __syncthreads -> vmcnt(0) drain
//       with zero overlap, every K-step.
// Fragment CONTENTS are bit-identical to r14 (same splits, same MFMA
// operand order) -> numerics unchanged.

typedef __attribute__((ext_vector_type(4))) float f32x4;
typedef __attribute__((ext_vector_type(8))) short bfr8;   // 8 x bf16 (4 VGPRs)
typedef _Float16 f16;
typedef __attribute__((ext_vector_type(2))) _Float16 f16x2;

__device__ __forceinline__ unsigned short f2bf(float f) {
  unsigned int u = __float_as_uint(f);
  u += 0x7fffu + ((u >> 16) & 1u);      // RNE
  return (unsigned short)(u >> 16);
}
__device__ __forceinline__ float bf2f(unsigned short h) {
  return __uint_as_float(((unsigned int)h) << 16);
}

__device__ __forceinline__ void gload16(const void* g, void* l) {
  __builtin_amdgcn_global_load_lds((const __attribute__((address_space(1))) void*)g,
                                   (__attribute__((address_space(3))) void*)l,
                                   16, 0, 0);
}

// g(x) = exp(log_g(x)): x+0.5 for x>=0, e^5*sigmoid(x) for x<0
__device__ __forceinline__ float g_of(float hv) {
  return (hv >= 0.f) ? (hv + 0.5f)
                     : 148.4131591025766f / (1.f + __expf(-hv));
}

// ---- pack W into pre-swizzled per-tile blocks + fp32 Wh^T; zero fcnt ----
// Output layout: wtp[((m*16+nt)*32+kt)*4096 ushorts] = one 8KB tile image:
//   image[n][chunk c][e 0..7] holds source chunk s = c ^ (n&7):
//     s in 0..3 -> hi bf16 of W[kt*32 + s*8 + e][nt*64 + n]   (RNE)
//     s in 4..7 -> lo bf16 (RNE of residual)
// gemm copies this linearly via global_load_lds -> swizzled LDS for free.
__global__ void prep_w2(const float* __restrict__ Wz, const float* __restrict__ Wh,
                        unsigned short* __restrict__ wtp, float* __restrict__ whT,
                        unsigned int* __restrict__ fcnt)
{
  int kt = blockIdx.x;   // 0..31
  int nt = blockIdx.y;   // 0..15
  int m  = blockIdx.z;   // 0 = Wz, 1 = Wh
  if (kt == 0 && nt == 0 && m == 0 && threadIdx.x == 0) *fcnt = 0u;
  __shared__ float tile[32][65];
  const float* W = m ? Wh : Wz;
  int n0 = nt * 64, k0 = kt * 32;
  int t = threadIdx.x;
  {
    int r = t >> 3, c0 = (t & 7) * 8;
    const float* src = &W[(size_t)(k0 + r) * 1024 + n0 + c0];
#pragma unroll
    for (int i = 0; i < 8; i++) tile[r][c0 + i] = src[i];
  }
  __syncthreads();
  unsigned short* out = wtp + ((size_t)(m * 16 + nt) * 32 + kt) * 4096;
  {
    int n = t >> 2;            // 0..63
    int cb = (t & 3) * 2;      // chunks cb, cb+1 (16 ushorts contiguous)
    unsigned int u[8];
#pragma unroll
    for (int q = 0; q < 8; q++) {
      unsigned short w2[2];
#pragma unroll
      for (int h = 0; h < 2; h++) {
        int e = q * 2 + h;
        int c = cb + (e >> 3), el = e & 7;
        int s = c ^ (n & 7);
        float v = tile[(s & 3) * 8 + el][n];
        unsigned short hi = f2bf(v);
        w2[h] = (s < 4) ? hi : f2bf(v - bf2f(hi));
      }
      u[q] = (unsigned int)w2[0] | ((unsigned int)w2[1] << 16);
    }
    uint4* dst = (uint4*)&out[(size_t)n * 64 + cb * 8];
    dst[0] = make_uint4(u[0], u[1], u[2], u[3]);
    dst[1] = make_uint4(u[4], u[5], u[6], u[7]);
  }
  if (m == 1) {                                   // fp32 Wh^T for fixup
    int n = t >> 2, kk0 = (t & 3) * 8;
    float* dstf = &whT[(size_t)(n0 + n) * 1024 + k0 + kk0];
#pragma unroll
    for (int i = 0; i < 8; i++) dstf[i] = tile[kk0 + i][n];
  }
}

// ---------------- dual-B split-bf16 GEMM -> fused (k, v) epilogue --------
__global__ __launch_bounds__(256, 2) void gemm_cv(
    const float* __restrict__ x,
    const unsigned short* __restrict__ wtp,
    const float* __restrict__ bz, const float* __restrict__ bhb,
    f16x2* __restrict__ cvbuf,
    unsigned int* __restrict__ fcnt, unsigned int* __restrict__ flist,
    unsigned int fcap)
{
  // combined hi|lo tiles, 128B rows, XOR-swizzled at 16B-chunk granularity
  __shared__ __align__(16) unsigned short Ac[2][8192];    // [128][64] x2 buf
  __shared__ __align__(16) unsigned short Bzs[2][4096];   // [64][64]  x2 buf
  __shared__ __align__(16) unsigned short Bhs[2][4096];
  int tid = threadIdx.x;
  int lane = tid & 63, wv = tid >> 6;
  int wr = wv >> 1, wc = wv & 1;
  int lrow = lane & 15, lq = lane >> 4;   // lq = k-chunk quarter 0..3

  // XCD swizzle (4096 % 8 == 0, bijective) — unchanged mapping
  int bid = blockIdx.x;
  int cpx = gridDim.x >> 3;
  int swz = (bid & 7) * cpx + (bid >> 3);
  int grp = swz >> 7, wi = swz & 127;
  int mt = grp * 8 + (wi & 7);      // 0..255
  int nt = wi >> 3;                 // 0..15
  int m0 = mt * 128, n0 = nt * 64;

  f32x4 accz[4][2], acch[4][2];
#pragma unroll
  for (int i = 0; i < 4; i++)
#pragma unroll
    for (int j = 0; j < 2; j++) {
      accz[i][j] = (f32x4){0.f, 0.f, 0.f, 0.f};
      acch[i][j] = (f32x4){0.f, 0.f, 0.f, 0.f};
    }

  // A staging map: thread -> (row art + p*32, k-locals ac4..ac4+3)
  int art = tid >> 3, ac4 = (tid & 7) * 4;
  int awb = art * 64 + ((((ac4 >> 3) ^ (art & 7)) << 3) | (ac4 & 4));
  const float* xp = x + (size_t)(m0 + art) * D_ + ac4;

  // fragment read offsets (row&7 == lrow&7 for all f/j -> chunk constant)
  int fch = (lq ^ (lrow & 7)) << 3;
  int aoff = (wr * 64 + lrow) * 64 + fch;   // + f*1024 ; lo = ^32
  int boff = (wc * 32 + lrow) * 64 + fch;   // + j*1024 ; lo = ^32

  // packed B source (linear copy == swizzled LDS image)
  const unsigned short* bsz = wtp + (size_t)nt * 131072 + tid * 8;
  const unsigned short* bsh = bsz + 2097152;   // + 16*32*4096

  uint4 xa[4];

  auto loadX = [&](int kt) {
#pragma unroll
    for (int p = 0; p < 4; p++)
      xa[p] = *(const uint4*)(xp + (size_t)p * 32 * D_ + kt * 32);
  };
  auto stageB = [&](int kt, int b) {
#pragma unroll
    for (int j = 0; j < 2; j++) {
      gload16(bsz + (size_t)kt * 4096 + j * 2048, &Bzs[b][j * 2048 + tid * 8]);
      gload16(bsh + (size_t)kt * 4096 + j * 2048, &Bhs[b][j * 2048 + tid * 8]);
    }
  };
  auto writeA = [&](int b) {
#pragma unroll
    for (int p = 0; p < 4; p++) {
      uint4 vu = xa[p];
      unsigned int hi01 = __builtin_amdgcn_perm(vu.y, vu.x, 0x07060302u);
      unsigned int hi23 = __builtin_amdgcn_perm(vu.w, vu.z, 0x07060302u);
      float l0 = __uint_as_float(vu.x) - __uint_as_float(vu.x & 0xffff0000u);
      float l1 = __uint_as_float(vu.y) - __uint_as_float(vu.y & 0xffff0000u);
      float l2 = __uint_as_float(vu.z) - __uint_as_float(vu.z & 0xffff0000u);
      float l3 = __uint_as_float(vu.w) - __uint_as_float(vu.w & 0xffff0000u);
      unsigned int lo01 = __builtin_amdgcn_perm(__float_as_uint(l1),
                                                __float_as_uint(l0), 0x07060302u);
      unsigned int lo23 = __builtin_amdgcn_perm(__float_as_uint(l3),
                                                __float_as_uint(l2), 0x07060302u);
      int bi = p * 2048 + awb;
      *(uint2*)&Ac[b][bi]      = make_uint2(hi01, hi23);
      *(uint2*)&Ac[b][bi ^ 32] = make_uint2(lo01, lo23);   // lo chunk = hi^4
    }
  };
  auto doMFMA = [&](int cur) {
    bfr8 ah[4], al[4], bzhv[2], bzlv[2], bhhv[2], bhlv[2];
#pragma unroll
    for (int f = 0; f < 4; f++) {
      ah[f] = *(const bfr8*)&Ac[cur][aoff + f * 1024];
      al[f] = *(const bfr8*)&Ac[cur][(aoff + f * 1024) ^ 32];
    }
#pragma unroll
    for (int j = 0; j < 2; j++) {
      bzhv[j] = *(const bfr8*)&Bzs[cur][boff + j * 1024];
      bzlv[j] = *(const bfr8*)&Bzs[cur][(boff + j * 1024) ^ 32];
      bhhv[j] = *(const bfr8*)&Bhs[cur][boff + j * 1024];
      bhlv[j] = *(const bfr8*)&Bhs[cur][(boff + j * 1024) ^ 32];
    }
#pragma unroll
    for (int i = 0; i < 4; i++)
#pragma unroll
      for (int j = 0; j < 2; j++) {
        accz[i][j] = __builtin_amdgcn_mfma_f32_16x16x32_bf16(ah[i], bzhv[j], accz[i][j], 0, 0, 0);
        accz[i][j] = __builtin_amdgcn_mfma_f32_16x16x32_bf16(al[i], bzhv[j], accz[i][j], 0, 0, 0);
        accz[i][j] = __builtin_amdgcn_mfma_f32_16x16x32_bf16(ah[i], bzlv[j], accz[i][j], 0, 0, 0);
        acch[i][j] = __builtin_amdgcn_mfma_f32_16x16x32_bf16(ah[i], bhhv[j], acch[i][j], 0, 0, 0);
        acch[i][j] = __builtin_amdgcn_mfma_f32_16x16x32_bf16(al[i], bhhv[j], acch[i][j], 0, 0, 0);
        acch[i][j] = __builtin_amdgcn_mfma_f32_16x16x32_bf16(ah[i], bhlv[j], acch[i][j], 0, 0, 0);
      }
  };

  // prologue: stage K-step 0 into buf0
  loadX(0);
  stageB(0, 0);
  writeA(0);
  __syncthreads();

  auto step = [&](int kt, int cur, int nxt) {
    loadX(kt + 1);            // x(t+1) -> regs (issue early)
    stageB(kt + 1, nxt);      // B(t+1) -> buf^1 (in flight across MFMA)
    doMFMA(cur);              // compute t; hides load latency
    writeA(nxt);              // split x(t+1) -> buf^1 (write late)
    __syncthreads();          // single vmcnt/lgkm drain per K-step
  };

#pragma unroll 1
  for (int kt = 0; kt < 30; kt += 2) {
    step(kt, 0, 1);
    step(kt + 1, 1, 0);
  }
  step(30, 0, 1);
  doMFMA(1);                  // K-step 31, no prefetch

  // ---- fused epilogue: store k (f16) and v = z*g(ht), flag razor sites ---
#pragma unroll
  for (int j = 0; j < 2; j++) {
    int col = n0 + wc * 32 + j * 16 + lrow;
    float kb = bz[col], hb = bhb[col];
#pragma unroll
    for (int i = 0; i < 4; i++) {
      int row0 = m0 + wr * 64 + i * 16 + lq * 4;
#pragma unroll
      for (int r = 0; r < 4; r++) {
        float kv = accz[i][j][r] + kb;
        float hv = acch[i][j][r] + hb;
        f16 kf = (f16)kv;
        float c  = 1.f / (1.f + __expf((float)kf));   // sigma(-k), from f16 k
        float v  = (1.f - c) * g_of(hv);              // z * g
        size_t off = (size_t)(row0 + r) * H_ + col;
        f16x2 pr; pr[0] = kf; pr[1] = (f16)v;
        cvbuf[off] = pr;
        if (__builtin_fabsf(hv) < 1e-3f) {        // log_g discontinuity guard
          unsigned int p = atomicAdd(fcnt, 1u);
          if (p < fcap) flist[p] = (unsigned int)off;
        }
      }
    }
  }
}

// ---- replicate np-ref ordering at razor sites: KC512 two-panel FMA ------
// LOCKED (r12/r13): two in-order FMA half-chains, halves summed, then bias.
__global__ void fixup_kc512(const float* __restrict__ x, const float* __restrict__ whT,
                            const float* __restrict__ bhb, f16x2* cvbuf,
                            const unsigned int* __restrict__ fcnt,
                            const unsigned int* __restrict__ flist, unsigned int fcap)
{
  unsigned int n = *fcnt; if (n > fcap) n = fcap;
  unsigned int gtid = blockIdx.x * blockDim.x + threadIdx.x;
  unsigned int nt = gridDim.x * blockDim.x;
  const unsigned int lim = (unsigned int)M_ * (unsigned int)H_;
  for (unsigned int i = gtid; i < n; i += nt) {
    unsigned int o = flist[i];
    if (o >= lim) continue;                      // never scribble OOB
    unsigned int row = o >> 10, col = o & 1023u;
    const float* xr = x + (size_t)row * D_;
    const float* wr = whT + (size_t)col * D_;    // contiguous in d
    float a1 = 0.f, a2 = 0.f;
    for (int d = 0; d < 512; d++)                // panel 0: in-order FMA
      a1 = fmaf(xr[d], wr[d], a1);
    for (int d = 512; d < 1024; d++)             // panel 1: in-order FMA
      a2 = fmaf(xr[d], wr[d], a2);
    float hs = (a1 + a2) + bhb[col];             // halves, then bias
    float g  = (hs >= 0.f) ? (hs + 0.5f)
                           : 148.4131591025766f / (1.f + __expf(-hs));
    f16x2 pr = cvbuf[o];
    float z  = 1.f / (1.f + __expf(-(float)pr[0]));   // sigmoid(k)
    pr[1] = (f16)(z * g);
    cvbuf[o] = pr;
  }
}

// ---------------- scan phase 1: per-chunk (C = prod c, V from 0) ----------
__global__ void scan_p1(const f16x2* __restrict__ cv,
                        float* __restrict__ Cc, float* __restrict__ Vv)
{
  int h = blockIdx.x * 256 + threadIdx.x;       // 0..1023
  int ch = blockIdx.y, b = blockIdx.z;
  size_t base = ((size_t)b * T_ + (size_t)ch * TC_) * H_ + h;
  float C = 1.f, V = 0.f;
#pragma unroll 4
  for (int i = 0; i < TC_; i++) {
    f16x2 p = cv[base + (size_t)i * H_];
    float c = 1.f / (1.f + __expf((float)p[0]));   // sigma(-k) in fp32
    V = fmaf(c, V, (float)p[1]);
    C *= c;
  }
  size_t o = ((size_t)b * NC_ + ch) * H_ + h;
  Cc[o] = C; Vv[o] = V;
}

// ---------------- scan phase 2: sequential chunk prefix -------------------
__global__ void scan_p2(const float* __restrict__ h0, const float* __restrict__ Cc,
                        const float* __restrict__ Vv, float* __restrict__ Hi)
{
  int idx = blockIdx.x * 256 + threadIdx.x;   // b*1024 + h, 8192 total
  float hs = g_of(h0[idx]);
  int b = idx >> 10, h = idx & 1023;
  for (int ch = 0; ch < NC_; ch++) {
    size_t o = ((size_t)b * NC_ + ch) * H_ + h;
    Hi[o] = hs;
    hs = fmaf(Cc[o], hs, Vv[o]);
  }
}

// ---------------- scan phase 3: stage chunk -> LDS, overwrite with h ------
__global__ void scan_p3(void* buf, const float* __restrict__ Hi)
{
  __shared__ f16x2 S[TC_][256];
  const f16x2* cv = (const f16x2*)buf;
  float* out = (float*)buf;
  int t = threadIdx.x;
  int hg = blockIdx.x, ch = blockIdx.y, b = blockIdx.z;
  int col = hg * 256 + t;
  size_t base = ((size_t)b * T_ + (size_t)ch * TC_) * H_ + col;
#pragma unroll 4
  for (int r = 0; r < TC_; r++)
    S[r][t] = cv[base + (size_t)r * H_];
  __syncthreads();
  float hs = Hi[((size_t)b * NC_ + ch) * H_ + col];
#pragma unroll 4
  for (int r = 0; r < TC_; r++) {
    f16x2 p = S[r][t];
    float c = 1.f / (1.f + __expf((float)p[0]));   // sigma(-k) in fp32
    hs = fmaf(c, hs, (float)p[1]);
    out[base + (size_t)r * H_] = hs;
  }
}

extern "C" void kernel_launch(void* const* d_in, const int* in_sizes, int n_in,
                              void* d_out, int out_size, void* d_ws, size_t ws_size,
                              hipStream_t stream)
{
  const float* x  = (const float*)d_in[0];
  const float* h0 = (const float*)d_in[1];
  const float* Wz = (const float*)d_in[2];
  const float* bz = (const float*)d_in[3];
  const float* Wh = (const float*)d_in[4];
  const float* bh = (const float*)d_in[5];
  char* ws = (char*)d_ws;

  // ws layout — total 20 MiB (robust to small ws_size)
  const size_t MiB = 1024u * 1024u;
  unsigned int* fcnt  = (unsigned int*)(ws);
  unsigned int* flist = (unsigned int*)(ws + 4096);
  const unsigned int fcap = 250u * 1024u;                  // <1 MiB list
  unsigned short* wtp = (unsigned short*)(ws + 2 * MiB);   // 8 MiB packed swizzled W tiles
  float* Cc = (float*)(ws + 10 * MiB);                     // 2 MiB
  float* Vv = (float*)(ws + 12 * MiB);                     // 2 MiB
  float* Hi = (float*)(ws + 14 * MiB);                     // 2 MiB
  float* whT = (float*)(ws + 16 * MiB);                    // 4 MiB [1024][1024]

  // d_out (exactly 128 MiB) holds interleaved (k,v) f16x2, overwritten by h.
  f16x2* cvbuf = (f16x2*)d_out;

  prep_w2<<<dim3(32, 16, 2), 256, 0, stream>>>(Wz, Wh, wtp, whT, fcnt);
  gemm_cv<<<4096, 256, 0, stream>>>(x, wtp, bz, bh, cvbuf, fcnt, flist, fcap);
  fixup_kc512<<<512, 256, 0, stream>>>(x, whT, bh, cvbuf, fcnt, flist, fcap);
  scan_p1<<<dim3(4, 64, 8), 256, 0, stream>>>(cvbuf, Cc, Vv);
  scan_p2<<<32, 256, 0, stream>>>(h0, Cc, Vv, Hi);
  scan_p3<<<dim3(4, 64, 8), 256, 0, stream>>>(d_out, Hi);
}